// Round 6
// baseline (187.677 us; speedup 1.0000x reference)
//
#include <hip/hip_runtime.h>
#include <hip/hip_bf16.h>

#define NN 8192
#define FIN 512
#define FOUT 256
#define FH 64                 // head-mean output cols
#define JSPLIT 32
#define JCHUNK (NN / JSPLIT)  // 256
#define STEPS (JCHUNK / 32)   // 8

typedef float f32x16 __attribute__((ext_vector_type(16)));
typedef short bf16x8 __attribute__((ext_vector_type(8)));
typedef unsigned short us8 __attribute__((ext_vector_type(8)));

static __device__ __forceinline__ unsigned short f2bf(float x) {
  unsigned int u = __builtin_bit_cast(unsigned int, x);
  unsigned int r = (u + 0x7fffu + ((u >> 16) & 1u)) >> 16;  // RNE
  return (unsigned short)r;
}
static __device__ __forceinline__ float bf2f(unsigned short u) {
  unsigned int v = ((unsigned int)u) << 16;
  return __builtin_bit_cast(float, v);
}
static __device__ __forceinline__ float fastexp2(float x) {
  float r;
  asm("v_exp_f32 %0, %1" : "=v"(r) : "v"(x));
  return r;
}

// ---- K0: pack_adj — 256 MB int32 adjacency -> 8 MB bitmask (HBM-saturating) ----
// One wave per row (8192 waves). Per iter: 8 independent 256B loads in flight
// (2 KB/wave x 32 waves/CU = 64 KB/CU outstanding -> BW-bound, not latency).
__global__ __launch_bounds__(256) void pack_adj(const int* __restrict__ adj,
                                                unsigned long long* __restrict__ mask) {
  const int wid = (blockIdx.x * 256 + threadIdx.x) >> 6;  // 0..8191 = row
  const int lane = threadIdx.x & 63;
  const int* rp = adj + (size_t)wid * NN;
  unsigned long long* mp = mask + (size_t)wid * (NN / 64);
#pragma unroll 1
  for (int it = 0; it < 16; ++it) {
    int v0 = rp[it * 512 + 0 * 64 + lane];
    int v1 = rp[it * 512 + 1 * 64 + lane];
    int v2 = rp[it * 512 + 2 * 64 + lane];
    int v3 = rp[it * 512 + 3 * 64 + lane];
    int v4 = rp[it * 512 + 4 * 64 + lane];
    int v5 = rp[it * 512 + 5 * 64 + lane];
    int v6 = rp[it * 512 + 6 * 64 + lane];
    int v7 = rp[it * 512 + 7 * 64 + lane];
    unsigned long long b0 = __ballot(v0 != 0);
    unsigned long long b1 = __ballot(v1 != 0);
    unsigned long long b2 = __ballot(v2 != 0);
    unsigned long long b3 = __ballot(v3 != 0);
    unsigned long long b4 = __ballot(v4 != 0);
    unsigned long long b5 = __ballot(v5 != 0);
    unsigned long long b6 = __ballot(v6 != 0);
    unsigned long long b7 = __ballot(v7 != 0);
    if (lane == 0) {
      mp[it * 8 + 0] = b0;
      mp[it * 8 + 1] = b1;
      mp[it * 8 + 2] = b2;
      mp[it * 8 + 3] = b3;
      mp[it * 8 + 4] = b4;
      mp[it * 8 + 5] = b5;
      mp[it * 8 + 6] = b6;
      mp[it * 8 + 7] = b7;
    }
  }
}

// ---- K1: prep_small — fold head-mean + attention vecs into W fragments ----
// Bw layout: [kt(32)][h(2)][nf(3)][kh(2)][n(32)][e(8)] bf16 (192 KB).
__global__ __launch_bounds__(256) void prep_small(const float* __restrict__ W,
                                                  const float* __restrict__ a,
                                                  unsigned short* __restrict__ Bw) {
  const int kt = blockIdx.x;  // 0..31
  __shared__ float wm[16][64];
  __shared__ float wt[16][2];
  const int t = threadIdx.x;
#pragma unroll
  for (int i = 0; i < 4; ++i) {
    const int idx = t + i * 256;
    const int kr = idx >> 6, c = idx & 63;
    const float* wr = W + (size_t)(kt * 16 + kr) * FOUT + c;
    wm[kr][c] = 0.25f * (wr[0] + wr[64] + wr[128] + wr[192]);
  }
  if (t < 32) {
    const int kr = t & 15, sel = t >> 4;
    const float* wr = W + (size_t)(kt * 16 + kr) * FOUT;
    const float* av = a + sel * FOUT;
    float s = 0.f;
    for (int n = 0; n < FOUT; ++n) s += wr[n] * av[n];
    wt[kr][sel] = s * 1.44269504f;
  }
  __syncthreads();
#pragma unroll
  for (int i = 0; i < 12; ++i) {
    const int idx = t + i * 256;  // within-kt offset < 3072
    const int e = idx & 7, n = (idx >> 3) & 31, r2 = idx >> 8;
    const int khb = r2 & 1, q = r2 >> 1;
    const int nf = q % 3, h = q / 3;
    const int k = khb * 8 + e;
    float v = nf < 2 ? wm[k][nf * 32 + n]
                     : (n == 0 ? wt[k][0] : (n == 1 ? wt[k][1] : 0.f));
    const unsigned short hi = f2bf(v);
    Bw[(size_t)kt * 3072 + idx] = (h == 0) ? hi : f2bf(v - bf2f(hi));
  }
}

// ---- K2: convert_x — x f32 -> hi/lo bf16 A-fragments ----
__global__ __launch_bounds__(256) void convert_x(const float* __restrict__ X,
                                                 unsigned short* __restrict__ xf) {
  const int f = blockIdx.x * 256 + threadIdx.x;  // < 524288
  const int r = f & 31, kh = (f >> 5) & 1, kt = (f >> 6) & 31, mw = f >> 11;
  const float* src = X + (size_t)(mw * 32 + r) * FIN + kt * 16 + kh * 8;
  const float4 v0 = *(const float4*)src;
  const float4 v1 = *(const float4*)(src + 4);
  const float vv[8] = {v0.x, v0.y, v0.z, v0.w, v1.x, v1.y, v1.z, v1.w};
  us8 vh, vl;
#pragma unroll
  for (int e = 0; e < 8; ++e) {
    const unsigned short hi = f2bf(vv[e]);
    vh[e] = hi;
    vl[e] = f2bf(vv[e] - bf2f(hi));
  }
  const size_t b0 = ((size_t)(mw * 32 + kt) * 4 + kh) * 256 + (size_t)r * 8;
  *(us8*)(xf + b0) = vh;
  *(us8*)(xf + b0 + 512) = vl;  // h stride = 512 shorts
}

// ---- K3: gemm_whm — Whm = x @ Wm (hi/lo 3-product MFMA) + s extraction ----
__global__ __launch_bounds__(192) void gemm_whm(const unsigned short* __restrict__ xf,
                                                const unsigned short* __restrict__ Bw,
                                                float* __restrict__ Whm,
                                                float* __restrict__ ssrc,
                                                float* __restrict__ sdst) {
  __shared__ float sred[32][2];
  const int mw = blockIdx.x;
  const int nf = threadIdx.x >> 6, lane = threadIdx.x & 63;
  const int l31 = lane & 31, kh = lane >> 5;
  f32x16 acc = (f32x16)(0.f);
  const unsigned short* ap = xf + ((size_t)(mw * 32) * 4 + kh) * 256 + l31 * 8;
  const unsigned short* bp = Bw + ((size_t)nf * 2 + kh) * 256 + l31 * 8;
#pragma unroll 4
  for (int kt = 0; kt < 32; ++kt) {
    const bf16x8 a_h = *(const bf16x8*)(ap + kt * 1024);
    const bf16x8 a_l = *(const bf16x8*)(ap + kt * 1024 + 512);
    const bf16x8 b_h = *(const bf16x8*)(bp + kt * 3072);
    const bf16x8 b_l = *(const bf16x8*)(bp + kt * 3072 + 1536);
    acc = __builtin_amdgcn_mfma_f32_32x32x16_bf16(a_h, b_h, acc, 0, 0, 0);
    acc = __builtin_amdgcn_mfma_f32_32x32x16_bf16(a_h, b_l, acc, 0, 0, 0);
    acc = __builtin_amdgcn_mfma_f32_32x32x16_bf16(a_l, b_h, acc, 0, 0, 0);
  }
  if (nf < 2) {
#pragma unroll
    for (int reg = 0; reg < 16; ++reg) {
      const int row = (reg & 3) + ((reg >> 2) << 3) + (kh << 2);
      Whm[(size_t)(mw * 32 + row) * FH + nf * 32 + l31] = acc[reg];
    }
  } else if (l31 < 2) {
#pragma unroll
    for (int reg = 0; reg < 16; ++reg) {
      const int row = (reg & 3) + ((reg >> 2) << 3) + (kh << 2);
      sred[row][l31] = acc[reg];
    }
  }
  __syncthreads();
  if (threadIdx.x < 32) {
    ssrc[mw * 32 + threadIdx.x] = sred[threadIdx.x][0];
    sdst[mw * 32 + threadIdx.x] = sred[threadIdx.x][1];
  }
}

// ---- K4: build_whb — Whm f32 -> Bg hi/lo B-fragments for gat_aggr ----
// Bg per jw (32 j): [h(2)][kc(2)][khb(2)][nf(2)][nn(32)][e(8)] = 4096 shorts.
__global__ __launch_bounds__(256) void build_whb(const float* __restrict__ Whm,
                                                 unsigned short* __restrict__ Bg) {
  const int idx = blockIdx.x * 256 + threadIdx.x;  // < 65536
  const int n = idx & 63, jo = idx >> 6;           // jo = j>>3 < 1024
  const int jw = jo >> 2, kc = (jo >> 1) & 1, khb = jo & 1;
  const int nf = n >> 5, nn = n & 31;
  us8 vh, vl;
#pragma unroll
  for (int e = 0; e < 8; ++e) {
    const float v = Whm[(size_t)(jo * 8 + e) * FH + n];
    const unsigned short hi = f2bf(v);
    vh[e] = hi;
    vl[e] = f2bf(v - bf2f(hi));
  }
  const size_t base =
      (size_t)jw * 4096 + (size_t)((kc * 2 + khb) * 2 + nf) * 256 + nn * 8;
  *(us8*)(Bg + base) = vh;           // h=0
  *(us8*)(Bg + base + 2048) = vl;    // h=1
}

// ---- K5: gat_aggr — bitmask adj, LDS-staged B slice, barrier-free loop ----
// grid 1024 = 32 bm x 32 bj; 512 thr / 8 waves; wave = 32 rows x 64 cols.
// 2 blocks/CU. Mask word per lane per step (L2-resident); B from LDS (lgkm).
#define GLL(G, L)                                                           \
  __builtin_amdgcn_global_load_lds(                                         \
      (const __attribute__((address_space(1))) unsigned int*)(G),           \
      (__attribute__((address_space(3))) unsigned int*)(L), 16, 0, 0)

#define GENB(V, E, B, SD)                         \
  {                                               \
    float tt = ss + (SD);                         \
    float lr = fmaxf(tt, 0.2f * tt);              \
    float pe = (B) ? fastexp2(lr) : 1.0f;         \
    unsigned short hb = f2bf(pe);                 \
    V[E] = (short)hb;                             \
    dacc += bf2f(hb);                             \
  }

__global__ __launch_bounds__(512, 4) void gat_aggr(
    const unsigned int* __restrict__ mask, const float* __restrict__ ssrc_g,
    const float* __restrict__ sdst_g, const unsigned short* __restrict__ Bg,
    unsigned short* __restrict__ Upb, float* __restrict__ Dp) {
  __shared__ unsigned short lbuf[STEPS * 4096];  // 64 KB: whole bj B slice
  const int bid = blockIdx.x;
  const int bj = bid & 31, bm = bid >> 5;
  const int wv = threadIdx.x >> 6, lane = threadIdx.x & 63;
  const int l31 = lane & 31, kh = lane >> 5;
  const int rbase = bm * 256;
  const int myrow = rbase + wv * 32 + l31;
  const int jb = bj * JCHUNK;
  const float ss = ssrc_g[myrow];
  const unsigned int* mrow = mask + (size_t)myrow * (NN / 32) + bj * STEPS;
  const float* sdp = sdst_g + jb + kh * 8;

  // ---- prologue: stage whole 64 KB B slice ----
  {
    const unsigned short* gs = Bg + (size_t)bj * (STEPS * 4096) +
                               (size_t)(wv * 8) * 512 + lane * 8;
#pragma unroll
    for (int c = 0; c < 8; ++c) GLL(gs + c * 512, &lbuf[(wv * 8 + c) * 512]);
  }
  unsigned int m_cur = mrow[0];

  f32x16 acc0 = (f32x16)(0.f), acc1 = (f32x16)(0.f);
  float dacc = 0.f;
  __syncthreads();  // B slice landed; only barrier in the kernel

  const unsigned short* lb0 = &lbuf[kh * 512 + l31 * 8];

#pragma unroll
  for (int t = 0; t < STEPS; ++t) {
    const unsigned int m_nxt = (t + 1 < STEPS) ? mrow[t + 1] : 0u;
    const unsigned int mm = m_cur >> (kh * 8);
    const unsigned short* tb = lb0 + (size_t)t * 4096;
    const bf16x8 b00 = *(const bf16x8*)(tb);          // kc0 h0 nf0
    const bf16x8 b01 = *(const bf16x8*)(tb + 2048);   // kc0 h1 nf0
    const bf16x8 b02 = *(const bf16x8*)(tb + 256);    // kc0 h0 nf1
    const bf16x8 b03 = *(const bf16x8*)(tb + 2304);   // kc0 h1 nf1
    const bf16x8 b10 = *(const bf16x8*)(tb + 1024);   // kc1 h0 nf0
    const bf16x8 b11 = *(const bf16x8*)(tb + 3072);   // kc1 h1 nf0
    const bf16x8 b12 = *(const bf16x8*)(tb + 1280);   // kc1 h0 nf1
    const bf16x8 b13 = *(const bf16x8*)(tb + 3328);   // kc1 h1 nf1
    bf16x8 af0, af1;
    {
      const float4 sA0 = *(const float4*)(sdp + t * 32);
      const float4 sB0 = *(const float4*)(sdp + t * 32 + 4);
      const float4 sA1 = *(const float4*)(sdp + t * 32 + 16);
      const float4 sB1 = *(const float4*)(sdp + t * 32 + 20);
      GENB(af0, 0, (mm >> 0) & 1u, sA0.x)
      GENB(af0, 1, (mm >> 1) & 1u, sA0.y)
      GENB(af0, 2, (mm >> 2) & 1u, sA0.z)
      GENB(af0, 3, (mm >> 3) & 1u, sA0.w)
      GENB(af0, 4, (mm >> 4) & 1u, sB0.x)
      GENB(af0, 5, (mm >> 5) & 1u, sB0.y)
      GENB(af0, 6, (mm >> 6) & 1u, sB0.z)
      GENB(af0, 7, (mm >> 7) & 1u, sB0.w)
      GENB(af1, 0, (mm >> 16) & 1u, sA1.x)
      GENB(af1, 1, (mm >> 17) & 1u, sA1.y)
      GENB(af1, 2, (mm >> 18) & 1u, sA1.z)
      GENB(af1, 3, (mm >> 19) & 1u, sA1.w)
      GENB(af1, 4, (mm >> 20) & 1u, sB1.x)
      GENB(af1, 5, (mm >> 21) & 1u, sB1.y)
      GENB(af1, 6, (mm >> 22) & 1u, sB1.z)
      GENB(af1, 7, (mm >> 23) & 1u, sB1.w)
    }
    acc0 = __builtin_amdgcn_mfma_f32_32x32x16_bf16(af0, b00, acc0, 0, 0, 0);
    acc0 = __builtin_amdgcn_mfma_f32_32x32x16_bf16(af0, b01, acc0, 0, 0, 0);
    acc1 = __builtin_amdgcn_mfma_f32_32x32x16_bf16(af0, b02, acc1, 0, 0, 0);
    acc1 = __builtin_amdgcn_mfma_f32_32x32x16_bf16(af0, b03, acc1, 0, 0, 0);
    acc0 = __builtin_amdgcn_mfma_f32_32x32x16_bf16(af1, b10, acc0, 0, 0, 0);
    acc0 = __builtin_amdgcn_mfma_f32_32x32x16_bf16(af1, b11, acc0, 0, 0, 0);
    acc1 = __builtin_amdgcn_mfma_f32_32x32x16_bf16(af1, b12, acc1, 0, 0, 0);
    acc1 = __builtin_amdgcn_mfma_f32_32x32x16_bf16(af1, b13, acc1, 0, 0, 0);
    m_cur = m_nxt;
  }

  // ---- D: lanes l, l+32 hold complementary kh halves of same row ----
  dacc += __shfl_xor(dacc, 32);
  if (lane < 32) Dp[(size_t)bj * NN + myrow] = dacc;

  // ---- U: C/D layout col=lane&31, row=(reg&3)+8*(reg>>2)+4*(lane>>5) ----
  unsigned short* ub = Upb + ((size_t)bj * NN + rbase + wv * 32) * FH;
#pragma unroll
  for (int reg = 0; reg < 16; ++reg) {
    const int rr = (reg & 3) + ((reg >> 2) << 3) + (kh << 2);
    ub[(size_t)rr * FH + l31] = f2bf(acc0[reg]);
    ub[(size_t)rr * FH + 32 + l31] = f2bf(acc1[reg]);
  }
}

// ---- K6: finalize — combine j-splits, divide ----
__global__ __launch_bounds__(256) void finalize(const unsigned short* __restrict__ Upb,
                                                const float* __restrict__ Dp,
                                                float* __restrict__ out) {
  const int idx = blockIdx.x * 256 + threadIdx.x;  // < 8192*64
  const int i = idx >> 6;
  float u = 0.f, d = 0.f;
#pragma unroll
  for (int s = 0; s < JSPLIT; ++s) {
    d += Dp[(size_t)s * NN + i];
    u += bf2f(Upb[(size_t)s * NN * FH + idx]);
  }
  out[idx] = u / d;
}

extern "C" void kernel_launch(void* const* d_in, const int* in_sizes, int n_in,
                              void* d_out, int out_size, void* d_ws, size_t ws_size,
                              hipStream_t stream) {
  const float* x = (const float*)d_in[0];
  const int* adj = (const int*)d_in[1];
  const float* W = (const float*)d_in[2];
  const float* a = (const float*)d_in[3];
  char* ws = (char*)d_ws;

  // ws layout (48 MB total; ws >= 49 MB proven in R1):
  //   xf   [0, 16 MB)   bf16 hi/lo x-fragments (dead after gemm_whm)
  //   Upb  [0, 32 MB)   bf16 U partials (32 splits) -- OVERLAPS xf
  //   Bg   [32, 34 MB)  bf16 hi/lo Whm B-fragments
  //   Whm  [34, 36 MB)  f32 head-mean of Wh
  //   Bw   36 MB +192 KB; ssrc +256K; sdst +288K; Dp +320K (1 MB)
  //   mask [40, 48 MB)  adj bitmask (u64)
  unsigned short* xf = (unsigned short*)ws;
  unsigned short* Upb = (unsigned short*)ws;
  unsigned short* Bg = (unsigned short*)(ws + ((size_t)32 << 20));
  float* Whm = (float*)(ws + ((size_t)34 << 20));
  unsigned short* Bw = (unsigned short*)(ws + ((size_t)36 << 20));
  float* ssrc = (float*)(ws + ((size_t)36 << 20) + (256u << 10));
  float* sdst = (float*)(ws + ((size_t)36 << 20) + (288u << 10));
  float* Dp = (float*)(ws + ((size_t)36 << 20) + (320u << 10));
  unsigned long long* mask = (unsigned long long*)(ws + ((size_t)40 << 20));
  float* out = (float*)d_out;

  pack_adj<<<2048, 256, 0, stream>>>(adj, mask);
  prep_small<<<32, 256, 0, stream>>>(W, a, Bw);
  convert_x<<<2048, 256, 0, stream>>>(x, xf);
  gemm_whm<<<256, 192, 0, stream>>>(xf, Bw, Whm, ssrc, sdst);
  build_whb<<<65536 / 256, 256, 0, stream>>>(Whm, Bg);
  gat_aggr<<<32 * JSPLIT, 512, 0, stream>>>((const unsigned int*)mask, ssrc, sdst,
                                            Bg, Upb, Dp);
  finalize<<<NN * FH / 256, 256, 0, stream>>>(Upb, Dp, out);
}

// Round 7
// 141.433 us; speedup vs baseline: 1.3270x; 1.3270x over previous
//
#include <hip/hip_runtime.h>
#include <hip/hip_bf16.h>

#define NN 8192
#define FIN 512
#define FOUT 256
#define FH 64                 // head-mean output cols
#define JSPLIT 32
#define JCHUNK (NN / JSPLIT)  // 256
#define STEPS (JCHUNK / 32)   // 8

typedef float f32x16 __attribute__((ext_vector_type(16)));
typedef short bf16x8 __attribute__((ext_vector_type(8)));
typedef unsigned short us8 __attribute__((ext_vector_type(8)));

static __device__ __forceinline__ unsigned short f2bf(float x) {
  unsigned int u = __builtin_bit_cast(unsigned int, x);
  unsigned int r = (u + 0x7fffu + ((u >> 16) & 1u)) >> 16;  // RNE
  return (unsigned short)r;
}
static __device__ __forceinline__ float bf2f(unsigned short u) {
  unsigned int v = ((unsigned int)u) << 16;
  return __builtin_bit_cast(float, v);
}
static __device__ __forceinline__ float fastexp2(float x) {
  float r;
  asm("v_exp_f32 %0, %1" : "=v"(r) : "v"(x));
  return r;
}

// ---- K0: pack_adj — adj int32 -> TRANSPOSED bitmask maskT[word][row] ----
// grid 1024 = 32 br x 32 bc; block 256 thr / 4 waves; 4 blocks/CU.
// Lane = one row; per iter reads 128 B (one full line) of its row, packs 32
// bits with v_lshl_or, stores coalesced (64 consecutive rows per word).
#define OR4(Q, K)                                      \
  m |= ((unsigned int)(Q).x << (K)) |                  \
       ((unsigned int)(Q).y << ((K) + 1)) |            \
       ((unsigned int)(Q).z << ((K) + 2)) |            \
       ((unsigned int)(Q).w << ((K) + 3));
__global__ __launch_bounds__(256) void pack_adj(const int* __restrict__ adj,
                                                unsigned int* __restrict__ maskT) {
  const int br = blockIdx.x & 31;  // row block: 256 rows
  const int bc = blockIdx.x >> 5;  // col block: 8 words (256 cols)
  const int w = threadIdx.x >> 6, lane = threadIdx.x & 63;
  const int row = br * 256 + w * 64 + lane;
  const int* rp = adj + (size_t)row * NN;
#pragma unroll 1
  for (int it = 0; it < 8; ++it) {
    const int cw = bc * 8 + it;
    const int4* p = (const int4*)(rp + cw * 32);
    const int4 q0 = p[0], q1 = p[1], q2 = p[2], q3 = p[3];
    const int4 q4 = p[4], q5 = p[5], q6 = p[6], q7 = p[7];
    unsigned int m = 0;
    OR4(q0, 0) OR4(q1, 4) OR4(q2, 8) OR4(q3, 12)
    OR4(q4, 16) OR4(q5, 20) OR4(q6, 24) OR4(q7, 28)
    maskT[(size_t)cw * NN + row] = m;
  }
}
#undef OR4

// ---- K1: prep_small — fold head-mean + attention vecs into W fragments ----
// Bw layout: [kt(32)][h(2)][nf(3)][kh(2)][n(32)][e(8)] bf16 (192 KB).
__global__ __launch_bounds__(256) void prep_small(const float* __restrict__ W,
                                                  const float* __restrict__ a,
                                                  unsigned short* __restrict__ Bw) {
  const int kt = blockIdx.x;  // 0..31
  __shared__ float wm[16][64];
  __shared__ float wt[16][2];
  const int t = threadIdx.x;
#pragma unroll
  for (int i = 0; i < 4; ++i) {
    const int idx = t + i * 256;
    const int kr = idx >> 6, c = idx & 63;
    const float* wr = W + (size_t)(kt * 16 + kr) * FOUT + c;
    wm[kr][c] = 0.25f * (wr[0] + wr[64] + wr[128] + wr[192]);
  }
  if (t < 32) {
    const int kr = t & 15, sel = t >> 4;
    const float* wr = W + (size_t)(kt * 16 + kr) * FOUT;
    const float* av = a + sel * FOUT;
    float s = 0.f;
    for (int n = 0; n < FOUT; ++n) s += wr[n] * av[n];
    wt[kr][sel] = s * 1.44269504f;
  }
  __syncthreads();
#pragma unroll
  for (int i = 0; i < 12; ++i) {
    const int idx = t + i * 256;  // within-kt offset < 3072
    const int e = idx & 7, n = (idx >> 3) & 31, r2 = idx >> 8;
    const int khb = r2 & 1, q = r2 >> 1;
    const int nf = q % 3, h = q / 3;
    const int k = khb * 8 + e;
    float v = nf < 2 ? wm[k][nf * 32 + n]
                     : (n == 0 ? wt[k][0] : (n == 1 ? wt[k][1] : 0.f));
    const unsigned short hi = f2bf(v);
    Bw[(size_t)kt * 3072 + idx] = (h == 0) ? hi : f2bf(v - bf2f(hi));
  }
}

// ---- K2: convert_x — x f32 -> hi/lo bf16 A-fragments ----
__global__ __launch_bounds__(256) void convert_x(const float* __restrict__ X,
                                                 unsigned short* __restrict__ xf) {
  const int f = blockIdx.x * 256 + threadIdx.x;  // < 524288
  const int r = f & 31, kh = (f >> 5) & 1, kt = (f >> 6) & 31, mw = f >> 11;
  const float* src = X + (size_t)(mw * 32 + r) * FIN + kt * 16 + kh * 8;
  const float4 v0 = *(const float4*)src;
  const float4 v1 = *(const float4*)(src + 4);
  const float vv[8] = {v0.x, v0.y, v0.z, v0.w, v1.x, v1.y, v1.z, v1.w};
  us8 vh, vl;
#pragma unroll
  for (int e = 0; e < 8; ++e) {
    const unsigned short hi = f2bf(vv[e]);
    vh[e] = hi;
    vl[e] = f2bf(vv[e] - bf2f(hi));
  }
  const size_t b0 = ((size_t)(mw * 32 + kt) * 4 + kh) * 256 + (size_t)r * 8;
  *(us8*)(xf + b0) = vh;
  *(us8*)(xf + b0 + 512) = vl;  // h stride = 512 shorts
}

// ---- K3: gemm_whm — Whm = x @ Wm (hi/lo 3-product MFMA) + s extraction ----
__global__ __launch_bounds__(192) void gemm_whm(const unsigned short* __restrict__ xf,
                                                const unsigned short* __restrict__ Bw,
                                                float* __restrict__ Whm,
                                                float* __restrict__ ssrc,
                                                float* __restrict__ sdst) {
  __shared__ float sred[32][2];
  const int mw = blockIdx.x;
  const int nf = threadIdx.x >> 6, lane = threadIdx.x & 63;
  const int l31 = lane & 31, kh = lane >> 5;
  f32x16 acc = (f32x16)(0.f);
  const unsigned short* ap = xf + ((size_t)(mw * 32) * 4 + kh) * 256 + l31 * 8;
  const unsigned short* bp = Bw + ((size_t)nf * 2 + kh) * 256 + l31 * 8;
#pragma unroll 4
  for (int kt = 0; kt < 32; ++kt) {
    const bf16x8 a_h = *(const bf16x8*)(ap + kt * 1024);
    const bf16x8 a_l = *(const bf16x8*)(ap + kt * 1024 + 512);
    const bf16x8 b_h = *(const bf16x8*)(bp + kt * 3072);
    const bf16x8 b_l = *(const bf16x8*)(bp + kt * 3072 + 1536);
    acc = __builtin_amdgcn_mfma_f32_32x32x16_bf16(a_h, b_h, acc, 0, 0, 0);
    acc = __builtin_amdgcn_mfma_f32_32x32x16_bf16(a_h, b_l, acc, 0, 0, 0);
    acc = __builtin_amdgcn_mfma_f32_32x32x16_bf16(a_l, b_h, acc, 0, 0, 0);
  }
  if (nf < 2) {
#pragma unroll
    for (int reg = 0; reg < 16; ++reg) {
      const int row = (reg & 3) + ((reg >> 2) << 3) + (kh << 2);
      Whm[(size_t)(mw * 32 + row) * FH + nf * 32 + l31] = acc[reg];
    }
  } else if (l31 < 2) {
#pragma unroll
    for (int reg = 0; reg < 16; ++reg) {
      const int row = (reg & 3) + ((reg >> 2) << 3) + (kh << 2);
      sred[row][l31] = acc[reg];
    }
  }
  __syncthreads();
  if (threadIdx.x < 32) {
    ssrc[mw * 32 + threadIdx.x] = sred[threadIdx.x][0];
    sdst[mw * 32 + threadIdx.x] = sred[threadIdx.x][1];
  }
}

// ---- K4: build_whb — Whm f32 -> Bg hi/lo B-fragments for gat_aggr ----
// Bg per jw (32 j): [h(2)][kc(2)][khb(2)][nf(2)][nn(32)][e(8)] = 4096 shorts.
__global__ __launch_bounds__(256) void build_whb(const float* __restrict__ Whm,
                                                 unsigned short* __restrict__ Bg) {
  const int idx = blockIdx.x * 256 + threadIdx.x;  // < 65536
  const int n = idx & 63, jo = idx >> 6;           // jo = j>>3 < 1024
  const int jw = jo >> 2, kc = (jo >> 1) & 1, khb = jo & 1;
  const int nf = n >> 5, nn = n & 31;
  us8 vh, vl;
#pragma unroll
  for (int e = 0; e < 8; ++e) {
    const float v = Whm[(size_t)(jo * 8 + e) * FH + n];
    const unsigned short hi = f2bf(v);
    vh[e] = hi;
    vl[e] = f2bf(v - bf2f(hi));
  }
  const size_t base =
      (size_t)jw * 4096 + (size_t)((kc * 2 + khb) * 2 + nf) * 256 + nn * 8;
  *(us8*)(Bg + base) = vh;           // h=0
  *(us8*)(Bg + base + 2048) = vl;    // h=1
}

// ---- K5: gat_aggr — branch-free GEN, transposed mask, LDS-staged B ----
// grid 1024 = 32 bm x 32 bj; 512 thr / 8 waves; wave = 32 rows x 64 cols.
// 2 blocks/CU (64 KB LDS). NO divergent branches in the main loop.
#define GLL(G, L)                                                           \
  __builtin_amdgcn_global_load_lds(                                         \
      (const __attribute__((address_space(1))) unsigned int*)(G),           \
      (__attribute__((address_space(3))) unsigned int*)(L), 16, 0, 0)

// Branch-proof: exp computed unconditionally; arithmetic select via fma.
#define GENB(V, E, BITF, SD)                         \
  {                                                  \
    float tt = ss + (SD);                            \
    float lr = fmaxf(tt, 0.2f * tt);                 \
    float ex = fastexp2(lr);                         \
    float pe = __builtin_fmaf((BITF), ex - 1.0f, 1.0f); \
    unsigned short hb = f2bf(pe);                    \
    V[E] = (short)hb;                                \
    dacc += bf2f(hb);                                \
  }

__global__ __launch_bounds__(512, 4) void gat_aggr(
    const unsigned int* __restrict__ maskT, const float* __restrict__ ssrc_g,
    const float* __restrict__ sdst_g, const unsigned short* __restrict__ Bg,
    unsigned short* __restrict__ Upb, float* __restrict__ Dp) {
  __shared__ unsigned short lbuf[STEPS * 4096];  // 64 KB: whole bj B slice
  const int bid = blockIdx.x;
  const int bj = bid & 31, bm = bid >> 5;
  const int wv = threadIdx.x >> 6, lane = threadIdx.x & 63;
  const int l31 = lane & 31, kh = lane >> 5;
  const int rbase = bm * 256;
  const int myrow = rbase + wv * 32 + l31;
  const int jb = bj * JCHUNK;
  const float ss = ssrc_g[myrow];
  const unsigned int* mrowT = maskT + (size_t)(bj * STEPS) * NN + myrow;
  const float* sdp = sdst_g + jb + kh * 8;

  // ---- prologue: stage whole 64 KB B slice ----
  {
    const unsigned short* gs = Bg + (size_t)bj * (STEPS * 4096) +
                               (size_t)(wv * 8) * 512 + lane * 8;
#pragma unroll
    for (int c = 0; c < 8; ++c) GLL(gs + c * 512, &lbuf[(wv * 8 + c) * 512]);
  }
  unsigned int m_cur = mrowT[0];

  f32x16 acc0 = (f32x16)(0.f), acc1 = (f32x16)(0.f);
  float dacc = 0.f;
  __syncthreads();  // B slice landed; only barrier in the kernel

  const unsigned short* lb0 = &lbuf[kh * 512 + l31 * 8];

#pragma unroll 1
  for (int t = 0; t < STEPS; ++t) {
    unsigned int m_nxt = m_cur;
    if (t + 1 < STEPS) m_nxt = mrowT[(size_t)(t + 1) * NN];  // uniform branch
    const unsigned int mm = m_cur >> (kh * 8);
    const unsigned short* tb = lb0 + (size_t)t * 4096;
    const bf16x8 b00 = *(const bf16x8*)(tb);          // kc0 h0 nf0
    const bf16x8 b01 = *(const bf16x8*)(tb + 2048);   // kc0 h1 nf0
    const bf16x8 b02 = *(const bf16x8*)(tb + 256);    // kc0 h0 nf1
    const bf16x8 b03 = *(const bf16x8*)(tb + 2304);   // kc0 h1 nf1
    const bf16x8 b10 = *(const bf16x8*)(tb + 1024);   // kc1 h0 nf0
    const bf16x8 b11 = *(const bf16x8*)(tb + 3072);   // kc1 h1 nf0
    const bf16x8 b12 = *(const bf16x8*)(tb + 1280);   // kc1 h0 nf1
    const bf16x8 b13 = *(const bf16x8*)(tb + 3328);   // kc1 h1 nf1
    bf16x8 af0, af1;
    {
      const float4 sA0 = *(const float4*)(sdp + t * 32);
      const float4 sB0 = *(const float4*)(sdp + t * 32 + 4);
      const float4 sA1 = *(const float4*)(sdp + t * 32 + 16);
      const float4 sB1 = *(const float4*)(sdp + t * 32 + 20);
      GENB(af0, 0, (float)((mm >> 0) & 1u), sA0.x)
      GENB(af0, 1, (float)((mm >> 1) & 1u), sA0.y)
      GENB(af0, 2, (float)((mm >> 2) & 1u), sA0.z)
      GENB(af0, 3, (float)((mm >> 3) & 1u), sA0.w)
      GENB(af0, 4, (float)((mm >> 4) & 1u), sB0.x)
      GENB(af0, 5, (float)((mm >> 5) & 1u), sB0.y)
      GENB(af0, 6, (float)((mm >> 6) & 1u), sB0.z)
      GENB(af0, 7, (float)((mm >> 7) & 1u), sB0.w)
      GENB(af1, 0, (float)((mm >> 16) & 1u), sA1.x)
      GENB(af1, 1, (float)((mm >> 17) & 1u), sA1.y)
      GENB(af1, 2, (float)((mm >> 18) & 1u), sA1.z)
      GENB(af1, 3, (float)((mm >> 19) & 1u), sA1.w)
      GENB(af1, 4, (float)((mm >> 20) & 1u), sB1.x)
      GENB(af1, 5, (float)((mm >> 21) & 1u), sB1.y)
      GENB(af1, 6, (float)((mm >> 22) & 1u), sB1.z)
      GENB(af1, 7, (float)((mm >> 23) & 1u), sB1.w)
    }
    acc0 = __builtin_amdgcn_mfma_f32_32x32x16_bf16(af0, b00, acc0, 0, 0, 0);
    acc0 = __builtin_amdgcn_mfma_f32_32x32x16_bf16(af0, b01, acc0, 0, 0, 0);
    acc1 = __builtin_amdgcn_mfma_f32_32x32x16_bf16(af0, b02, acc1, 0, 0, 0);
    acc1 = __builtin_amdgcn_mfma_f32_32x32x16_bf16(af0, b03, acc1, 0, 0, 0);
    acc0 = __builtin_amdgcn_mfma_f32_32x32x16_bf16(af1, b10, acc0, 0, 0, 0);
    acc0 = __builtin_amdgcn_mfma_f32_32x32x16_bf16(af1, b11, acc0, 0, 0, 0);
    acc1 = __builtin_amdgcn_mfma_f32_32x32x16_bf16(af1, b12, acc1, 0, 0, 0);
    acc1 = __builtin_amdgcn_mfma_f32_32x32x16_bf16(af1, b13, acc1, 0, 0, 0);
    m_cur = m_nxt;
  }

  // ---- D: lanes l, l+32 hold complementary kh halves of same row ----
  dacc += __shfl_xor(dacc, 32);
  if (lane < 32) Dp[(size_t)bj * NN + myrow] = dacc;

  // ---- U: C/D layout col=lane&31, row=(reg&3)+8*(reg>>2)+4*(lane>>5) ----
  unsigned short* ub = Upb + ((size_t)bj * NN + rbase + wv * 32) * FH;
#pragma unroll
  for (int reg = 0; reg < 16; ++reg) {
    const int rr = (reg & 3) + ((reg >> 2) << 3) + (kh << 2);
    ub[(size_t)rr * FH + l31] = f2bf(acc0[reg]);
    ub[(size_t)rr * FH + 32 + l31] = f2bf(acc1[reg]);
  }
}

// ---- K6: finalize — combine j-splits, divide ----
__global__ __launch_bounds__(256) void finalize(const unsigned short* __restrict__ Upb,
                                                const float* __restrict__ Dp,
                                                float* __restrict__ out) {
  const int idx = blockIdx.x * 256 + threadIdx.x;  // < 8192*64
  const int i = idx >> 6;
  float u = 0.f, d = 0.f;
#pragma unroll
  for (int s = 0; s < JSPLIT; ++s) {
    d += Dp[(size_t)s * NN + i];
    u += bf2f(Upb[(size_t)s * NN * FH + idx]);
  }
  out[idx] = u / d;
}

extern "C" void kernel_launch(void* const* d_in, const int* in_sizes, int n_in,
                              void* d_out, int out_size, void* d_ws, size_t ws_size,
                              hipStream_t stream) {
  const float* x = (const float*)d_in[0];
  const int* adj = (const int*)d_in[1];
  const float* W = (const float*)d_in[2];
  const float* a = (const float*)d_in[3];
  char* ws = (char*)d_ws;

  // ws layout (48 MB):
  //   xf    [0, 16 MB)   bf16 hi/lo x-fragments (dead after gemm_whm)
  //   Upb   [0, 32 MB)   bf16 U partials (32 splits) -- OVERLAPS xf
  //   Bg    [32, 34 MB)  bf16 hi/lo Whm B-fragments
  //   Whm   [34, 36 MB)  f32 head-mean of Wh
  //   Bw    36 MB +192 KB; ssrc +256K; sdst +288K; Dp +320K (1 MB)
  //   maskT [40, 48 MB)  transposed adj bitmask (u32 words x 8192 rows)
  unsigned short* xf = (unsigned short*)ws;
  unsigned short* Upb = (unsigned short*)ws;
  unsigned short* Bg = (unsigned short*)(ws + ((size_t)32 << 20));
  float* Whm = (float*)(ws + ((size_t)34 << 20));
  unsigned short* Bw = (unsigned short*)(ws + ((size_t)36 << 20));
  float* ssrc = (float*)(ws + ((size_t)36 << 20) + (256u << 10));
  float* sdst = (float*)(ws + ((size_t)36 << 20) + (288u << 10));
  float* Dp = (float*)(ws + ((size_t)36 << 20) + (320u << 10));
  unsigned int* maskT = (unsigned int*)(ws + ((size_t)40 << 20));
  float* out = (float*)d_out;

  pack_adj<<<1024, 256, 0, stream>>>(adj, maskT);
  prep_small<<<32, 256, 0, stream>>>(W, a, Bw);
  convert_x<<<2048, 256, 0, stream>>>(x, xf);
  gemm_whm<<<256, 192, 0, stream>>>(xf, Bw, Whm, ssrc, sdst);
  build_whb<<<65536 / 256, 256, 0, stream>>>(Whm, Bg);
  gat_aggr<<<32 * JSPLIT, 512, 0, stream>>>(maskT, ssrc, sdst, Bg, Upb, Dp);
  finalize<<<NN * FH / 256, 256, 0, stream>>>(Upb, Dp, out);
}

// Round 8
// 123.575 us; speedup vs baseline: 1.5187x; 1.1445x over previous
//
#include <hip/hip_runtime.h>
#include <hip/hip_bf16.h>

#define NN 8192
#define FIN 512
#define FOUT 256
#define FH 64                 // head-mean output cols
#define JSPLIT 32
#define JCHUNK (NN / JSPLIT)  // 256
#define STEPS (JCHUNK / 32)   // 8

typedef float f32x16 __attribute__((ext_vector_type(16)));
typedef short bf16x8 __attribute__((ext_vector_type(8)));
typedef unsigned short us8 __attribute__((ext_vector_type(8)));
typedef unsigned int uint32x4 __attribute__((ext_vector_type(4)));

static __device__ __forceinline__ unsigned short f2bf(float x) {
  unsigned int u = __builtin_bit_cast(unsigned int, x);
  unsigned int r = (u + 0x7fffu + ((u >> 16) & 1u)) >> 16;  // RNE
  return (unsigned short)r;
}
static __device__ __forceinline__ float bf2f(unsigned short u) {
  unsigned int v = ((unsigned int)u) << 16;
  return __builtin_bit_cast(float, v);
}
static __device__ __forceinline__ float fastexp2(float x) {
  float r;
  asm("v_exp_f32 %0, %1" : "=v"(r) : "v"(x));
  return r;
}

// ---- K0: pack_adj — coalesced ballot pack: adj -> mask[row][128] u64 ----
// Wave = one row; per iter 8 fully-coalesced 64-lane loads + __ballot.
// 8 loads x 256 B in flight per wave, 32 waves/CU -> HBM-BW-bound.
__global__ __launch_bounds__(256) void pack_adj(const int* __restrict__ adj,
                                                unsigned long long* __restrict__ mask) {
  const int wid = (blockIdx.x * 256 + threadIdx.x) >> 6;  // 0..8191 = row
  const int lane = threadIdx.x & 63;
  const int* rp = adj + (size_t)wid * NN;
  unsigned long long* mp = mask + (size_t)wid * (NN / 64);
#pragma unroll 1
  for (int it = 0; it < 16; ++it) {
    int v0 = rp[it * 512 + 0 * 64 + lane];
    int v1 = rp[it * 512 + 1 * 64 + lane];
    int v2 = rp[it * 512 + 2 * 64 + lane];
    int v3 = rp[it * 512 + 3 * 64 + lane];
    int v4 = rp[it * 512 + 4 * 64 + lane];
    int v5 = rp[it * 512 + 5 * 64 + lane];
    int v6 = rp[it * 512 + 6 * 64 + lane];
    int v7 = rp[it * 512 + 7 * 64 + lane];
    unsigned long long b0 = __ballot(v0 != 0);
    unsigned long long b1 = __ballot(v1 != 0);
    unsigned long long b2 = __ballot(v2 != 0);
    unsigned long long b3 = __ballot(v3 != 0);
    unsigned long long b4 = __ballot(v4 != 0);
    unsigned long long b5 = __ballot(v5 != 0);
    unsigned long long b6 = __ballot(v6 != 0);
    unsigned long long b7 = __ballot(v7 != 0);
    if (lane == 0) {
      mp[it * 8 + 0] = b0;
      mp[it * 8 + 1] = b1;
      mp[it * 8 + 2] = b2;
      mp[it * 8 + 3] = b3;
      mp[it * 8 + 4] = b4;
      mp[it * 8 + 5] = b5;
      mp[it * 8 + 6] = b6;
      mp[it * 8 + 7] = b7;
    }
  }
}

// ---- K1: prep_small — fold head-mean + attention vecs into W fragments ----
// Bw layout: [kt(32)][h(2)][nf(3)][kh(2)][n(32)][e(8)] bf16 (192 KB).
__global__ __launch_bounds__(256) void prep_small(const float* __restrict__ W,
                                                  const float* __restrict__ a,
                                                  unsigned short* __restrict__ Bw) {
  const int kt = blockIdx.x;  // 0..31
  __shared__ float wm[16][64];
  __shared__ float wt[16][2];
  const int t = threadIdx.x;
#pragma unroll
  for (int i = 0; i < 4; ++i) {
    const int idx = t + i * 256;
    const int kr = idx >> 6, c = idx & 63;
    const float* wr = W + (size_t)(kt * 16 + kr) * FOUT + c;
    wm[kr][c] = 0.25f * (wr[0] + wr[64] + wr[128] + wr[192]);
  }
  if (t < 32) {
    const int kr = t & 15, sel = t >> 4;
    const float* wr = W + (size_t)(kt * 16 + kr) * FOUT;
    const float* av = a + sel * FOUT;
    float s = 0.f;
    for (int n = 0; n < FOUT; ++n) s += wr[n] * av[n];
    wt[kr][sel] = s * 1.44269504f;
  }
  __syncthreads();
#pragma unroll
  for (int i = 0; i < 12; ++i) {
    const int idx = t + i * 256;  // within-kt offset < 3072
    const int e = idx & 7, n = (idx >> 3) & 31, r2 = idx >> 8;
    const int khb = r2 & 1, q = r2 >> 1;
    const int nf = q % 3, h = q / 3;
    const int k = khb * 8 + e;
    float v = nf < 2 ? wm[k][nf * 32 + n]
                     : (n == 0 ? wt[k][0] : (n == 1 ? wt[k][1] : 0.f));
    const unsigned short hi = f2bf(v);
    Bw[(size_t)kt * 3072 + idx] = (h == 0) ? hi : f2bf(v - bf2f(hi));
  }
}

// ---- K2: convert_x — x f32 -> hi/lo bf16 A-fragments ----
__global__ __launch_bounds__(256) void convert_x(const float* __restrict__ X,
                                                 unsigned short* __restrict__ xf) {
  const int f = blockIdx.x * 256 + threadIdx.x;  // < 524288
  const int r = f & 31, kh = (f >> 5) & 1, kt = (f >> 6) & 31, mw = f >> 11;
  const float* src = X + (size_t)(mw * 32 + r) * FIN + kt * 16 + kh * 8;
  const float4 v0 = *(const float4*)src;
  const float4 v1 = *(const float4*)(src + 4);
  const float vv[8] = {v0.x, v0.y, v0.z, v0.w, v1.x, v1.y, v1.z, v1.w};
  us8 vh, vl;
#pragma unroll
  for (int e = 0; e < 8; ++e) {
    const unsigned short hi = f2bf(vv[e]);
    vh[e] = hi;
    vl[e] = f2bf(vv[e] - bf2f(hi));
  }
  const size_t b0 = ((size_t)(mw * 32 + kt) * 4 + kh) * 256 + (size_t)r * 8;
  *(us8*)(xf + b0) = vh;
  *(us8*)(xf + b0 + 512) = vl;  // h stride = 512 shorts
}

// ---- K3: gemm_whm — Whm = x @ Wm (hi/lo MFMA); writes Bg fragments + s ----
// Epilogue maps C-frag (row,col) directly into Bg layout (build_whb folded in).
__global__ __launch_bounds__(192) void gemm_whm(const unsigned short* __restrict__ xf,
                                                const unsigned short* __restrict__ Bw,
                                                unsigned short* __restrict__ Bg,
                                                float* __restrict__ ssrc,
                                                float* __restrict__ sdst) {
  __shared__ float sred[32][2];
  const int mw = blockIdx.x;
  const int nf = threadIdx.x >> 6, lane = threadIdx.x & 63;
  const int l31 = lane & 31, kh = lane >> 5;
  f32x16 acc = (f32x16)(0.f);
  const unsigned short* ap = xf + ((size_t)(mw * 32) * 4 + kh) * 256 + l31 * 8;
  const unsigned short* bp = Bw + ((size_t)nf * 2 + kh) * 256 + l31 * 8;
#pragma unroll 4
  for (int kt = 0; kt < 32; ++kt) {
    const bf16x8 a_h = *(const bf16x8*)(ap + kt * 1024);
    const bf16x8 a_l = *(const bf16x8*)(ap + kt * 1024 + 512);
    const bf16x8 b_h = *(const bf16x8*)(bp + kt * 3072);
    const bf16x8 b_l = *(const bf16x8*)(bp + kt * 3072 + 1536);
    acc = __builtin_amdgcn_mfma_f32_32x32x16_bf16(a_h, b_h, acc, 0, 0, 0);
    acc = __builtin_amdgcn_mfma_f32_32x32x16_bf16(a_h, b_l, acc, 0, 0, 0);
    acc = __builtin_amdgcn_mfma_f32_32x32x16_bf16(a_l, b_h, acc, 0, 0, 0);
  }
  if (nf < 2) {
    // Bg per jw(=mw): [h(2)][kc(2)][khb(2)][nf(2)][nn(32)][e(8)] shorts.
    // C row = (reg&3)+((reg>>2)<<3)+(kh<<2) => e=(reg&3)|(kh<<2),
    // khb=(reg>>2)&1, kc=reg>>3; col = nf*32+l31 => nn=l31.
    unsigned short* bgw = Bg + (size_t)mw * 4096;
#pragma unroll
    for (int reg = 0; reg < 16; ++reg) {
      const float v = acc[reg];
      const unsigned short hi = f2bf(v);
      const unsigned short lo = f2bf(v - bf2f(hi));
      const int e = (reg & 3) | (kh << 2);
      const int khb = (reg >> 2) & 1;
      const int kc = reg >> 3;
      const size_t off =
          (size_t)(((kc * 2 + khb) * 2 + nf) * 256) + l31 * 8 + e;
      bgw[off] = hi;
      bgw[off + 2048] = lo;
    }
  } else if (l31 < 2) {
#pragma unroll
    for (int reg = 0; reg < 16; ++reg) {
      const int row = (reg & 3) + ((reg >> 2) << 3) + (kh << 2);
      sred[row][l31] = acc[reg];
    }
  }
  __syncthreads();
  if (threadIdx.x < 32) {
    ssrc[mw * 32 + threadIdx.x] = sred[threadIdx.x][0];
    sdst[mw * 32 + threadIdx.x] = sred[threadIdx.x][1];
  }
}

// ---- K5: gat_aggr — slim GEN (pre-exp select + cvt_pk), LDS-staged B ----
// grid 1024 = 32 bm x 32 bj; 512 thr / 8 waves; wave = 32 rows x 64 cols.
// 2 blocks/CU (64 KB LDS). No divergent branches; one barrier total.
#define GLL(G, L)                                                           \
  __builtin_amdgcn_global_load_lds(                                         \
      (const __attribute__((address_space(1))) unsigned int*)(G),           \
      (__attribute__((address_space(3))) unsigned int*)(L), 16, 0, 0)

// p = exp2( bit ? lr : 0 )  -> exact 1.0 for non-edges; dacc sums raw f32 p.
#define PEL(P, MM, B, SD)                    \
  float P;                                   \
  {                                          \
    float tt = ss + (SD);                    \
    float lr = fmaxf(tt, 0.2f * tt);         \
    lr = (((MM) >> (B)) & 1u) ? lr : 0.0f;   \
    P = fastexp2(lr);                        \
    dacc += P;                               \
  }

#define GENAF(AF, MM, BB, SA, SB)                                         \
  {                                                                       \
    PEL(p0, MM, (BB) + 0, (SA).x) PEL(p1, MM, (BB) + 1, (SA).y)           \
    PEL(p2, MM, (BB) + 2, (SA).z) PEL(p3, MM, (BB) + 3, (SA).w)           \
    PEL(p4, MM, (BB) + 4, (SB).x) PEL(p5, MM, (BB) + 5, (SB).y)           \
    PEL(p6, MM, (BB) + 6, (SB).z) PEL(p7, MM, (BB) + 7, (SB).w)           \
    unsigned int w0, w1, w2, w3;                                          \
    asm("v_cvt_pk_bf16_f32 %0, %1, %2" : "=v"(w0) : "v"(p0), "v"(p1));    \
    asm("v_cvt_pk_bf16_f32 %0, %1, %2" : "=v"(w1) : "v"(p2), "v"(p3));    \
    asm("v_cvt_pk_bf16_f32 %0, %1, %2" : "=v"(w2) : "v"(p4), "v"(p5));    \
    asm("v_cvt_pk_bf16_f32 %0, %1, %2" : "=v"(w3) : "v"(p6), "v"(p7));    \
    const uint32x4 uv = {w0, w1, w2, w3};                                 \
    AF = __builtin_bit_cast(bf16x8, uv);                                  \
  }

__global__ __launch_bounds__(512, 4) void gat_aggr(
    const unsigned long long* __restrict__ mask, const float* __restrict__ ssrc_g,
    const float* __restrict__ sdst_g, const unsigned short* __restrict__ Bg,
    unsigned short* __restrict__ Upb, float* __restrict__ Dp) {
  __shared__ unsigned short lbuf[STEPS * 4096];  // 64 KB: whole bj B slice
  const int bid = blockIdx.x;
  const int bj = bid & 31, bm = bid >> 5;
  const int wv = threadIdx.x >> 6, lane = threadIdx.x & 63;
  const int l31 = lane & 31, kh = lane >> 5;
  const int rbase = bm * 256;
  const int myrow = rbase + wv * 32 + l31;
  const int jb = bj * JCHUNK;
  const float ss = ssrc_g[myrow];
  // u64 words covering this bj's 256 cols: mask[myrow][bj*4 .. bj*4+3]
  const uint2* mrow = (const uint2*)(mask + (size_t)myrow * (NN / 64) + bj * 4);
  const float* sdp = sdst_g + jb + kh * 8;

  // ---- prologue: stage whole 64 KB B slice ----
  {
    const unsigned short* gs = Bg + (size_t)bj * (STEPS * 4096) +
                               (size_t)(wv * 8) * 512 + lane * 8;
#pragma unroll
    for (int c = 0; c < 8; ++c) GLL(gs + c * 512, &lbuf[(wv * 8 + c) * 512]);
  }
  uint2 mq = mrow[0];

  f32x16 acc0 = (f32x16)(0.f), acc1 = (f32x16)(0.f);
  float dacc = 0.f;
  __syncthreads();  // B slice landed; only barrier in the kernel

  const unsigned short* lb0 = &lbuf[kh * 512 + l31 * 8];

#define HALFSTEP(T, M32)                                                      \
  {                                                                           \
    const unsigned int mm = (M32) >> (kh * 8);                                \
    const unsigned short* tb = lb0 + (size_t)(T) * 4096;                      \
    const bf16x8 b00 = *(const bf16x8*)(tb);          /* kc0 h0 nf0 */        \
    const bf16x8 b01 = *(const bf16x8*)(tb + 2048);   /* kc0 h1 nf0 */        \
    const bf16x8 b02 = *(const bf16x8*)(tb + 256);    /* kc0 h0 nf1 */        \
    const bf16x8 b03 = *(const bf16x8*)(tb + 2304);   /* kc0 h1 nf1 */        \
    const bf16x8 b10 = *(const bf16x8*)(tb + 1024);   /* kc1 h0 nf0 */        \
    const bf16x8 b11 = *(const bf16x8*)(tb + 3072);   /* kc1 h1 nf0 */        \
    const bf16x8 b12 = *(const bf16x8*)(tb + 1280);   /* kc1 h0 nf1 */        \
    const bf16x8 b13 = *(const bf16x8*)(tb + 3328);   /* kc1 h1 nf1 */        \
    const float4 sA0 = *(const float4*)(sdp + (T) * 32);                      \
    const float4 sB0 = *(const float4*)(sdp + (T) * 32 + 4);                  \
    const float4 sA1 = *(const float4*)(sdp + (T) * 32 + 16);                 \
    const float4 sB1 = *(const float4*)(sdp + (T) * 32 + 20);                 \
    bf16x8 af0, af1;                                                          \
    GENAF(af0, mm, 0, sA0, sB0)                                               \
    GENAF(af1, mm, 16, sA1, sB1)                                              \
    acc0 = __builtin_amdgcn_mfma_f32_32x32x16_bf16(af0, b00, acc0, 0, 0, 0);  \
    acc0 = __builtin_amdgcn_mfma_f32_32x32x16_bf16(af0, b01, acc0, 0, 0, 0);  \
    acc1 = __builtin_amdgcn_mfma_f32_32x32x16_bf16(af0, b02, acc1, 0, 0, 0);  \
    acc1 = __builtin_amdgcn_mfma_f32_32x32x16_bf16(af0, b03, acc1, 0, 0, 0);  \
    acc0 = __builtin_amdgcn_mfma_f32_32x32x16_bf16(af1, b10, acc0, 0, 0, 0);  \
    acc0 = __builtin_amdgcn_mfma_f32_32x32x16_bf16(af1, b11, acc0, 0, 0, 0);  \
    acc1 = __builtin_amdgcn_mfma_f32_32x32x16_bf16(af1, b12, acc1, 0, 0, 0);  \
    acc1 = __builtin_amdgcn_mfma_f32_32x32x16_bf16(af1, b13, acc1, 0, 0, 0);  \
  }

#pragma unroll 1
  for (int tp = 0; tp < 4; ++tp) {
    uint2 mnxt = mq;
    if (tp + 1 < 4) mnxt = mrow[tp + 1];  // uniform branch
    HALFSTEP(2 * tp, mq.x)
    HALFSTEP(2 * tp + 1, mq.y)
    mq = mnxt;
  }
#undef HALFSTEP

  // ---- D: lanes l, l+32 hold complementary kh halves of same row ----
  dacc += __shfl_xor(dacc, 32);
  if (lane < 32) Dp[(size_t)bj * NN + myrow] = dacc;

  // ---- U: C/D layout col=lane&31, row=(reg&3)+8*(reg>>2)+4*(lane>>5) ----
  unsigned short* ub = Upb + ((size_t)bj * NN + rbase + wv * 32) * FH;
#pragma unroll
  for (int reg = 0; reg < 16; ++reg) {
    const int rr = (reg & 3) + ((reg >> 2) << 3) + (kh << 2);
    ub[(size_t)rr * FH + l31] = f2bf(acc0[reg]);
    ub[(size_t)rr * FH + 32 + l31] = f2bf(acc1[reg]);
  }
}

// ---- K6: finalize — combine j-splits, divide ----
__global__ __launch_bounds__(256) void finalize(const unsigned short* __restrict__ Upb,
                                                const float* __restrict__ Dp,
                                                float* __restrict__ out) {
  const int idx = blockIdx.x * 256 + threadIdx.x;  // < 8192*64
  const int i = idx >> 6;
  float u = 0.f, d = 0.f;
#pragma unroll
  for (int s = 0; s < JSPLIT; ++s) {
    d += Dp[(size_t)s * NN + i];
    u += bf2f(Upb[(size_t)s * NN * FH + idx]);
  }
  out[idx] = u / d;
}

extern "C" void kernel_launch(void* const* d_in, const int* in_sizes, int n_in,
                              void* d_out, int out_size, void* d_ws, size_t ws_size,
                              hipStream_t stream) {
  const float* x = (const float*)d_in[0];
  const int* adj = (const int*)d_in[1];
  const float* W = (const float*)d_in[2];
  const float* a = (const float*)d_in[3];
  char* ws = (char*)d_ws;

  // ws layout (48 MB):
  //   xf    [0, 16 MB)   bf16 hi/lo x-fragments (dead after gemm_whm)
  //   Upb   [0, 32 MB)   bf16 U partials (32 splits) -- OVERLAPS xf
  //   Bg    [32, 34 MB)  bf16 hi/lo Whm B-fragments (written by gemm_whm)
  //   Bw    36 MB +192 KB; ssrc +256K; sdst +288K; Dp +320K (1 MB)
  //   mask  [40, 48 MB)  row-major adj bitmask u64 [8192][128]
  unsigned short* xf = (unsigned short*)ws;
  unsigned short* Upb = (unsigned short*)ws;
  unsigned short* Bg = (unsigned short*)(ws + ((size_t)32 << 20));
  unsigned short* Bw = (unsigned short*)(ws + ((size_t)36 << 20));
  float* ssrc = (float*)(ws + ((size_t)36 << 20) + (256u << 10));
  float* sdst = (float*)(ws + ((size_t)36 << 20) + (288u << 10));
  float* Dp = (float*)(ws + ((size_t)36 << 20) + (320u << 10));
  unsigned long long* mask = (unsigned long long*)(ws + ((size_t)40 << 20));
  float* out = (float*)d_out;

  pack_adj<<<2048, 256, 0, stream>>>(adj, mask);
  prep_small<<<32, 256, 0, stream>>>(W, a, Bw);
  convert_x<<<2048, 256, 0, stream>>>(x, xf);
  gemm_whm<<<256, 192, 0, stream>>>(xf, Bw, Bg, ssrc, sdst);
  gat_aggr<<<32 * JSPLIT, 512, 0, stream>>>(mask, ssrc, sdst, Bg, Upb, Dp);
  finalize<<<NN * FH / 256, 256, 0, stream>>>(Upb, Dp, out);
}

// Round 9
// 105.798 us; speedup vs baseline: 1.7739x; 1.1680x over previous
//
#include <hip/hip_runtime.h>
#include <hip/hip_bf16.h>

#define NN 8192
#define FIN 512
#define FOUT 256
#define FH 64                 // head-mean output cols
#define JSPLIT 32
#define JCHUNK (NN / JSPLIT)  // 256
#define STEPS (JCHUNK / 32)   // 8

typedef float f32x16 __attribute__((ext_vector_type(16)));
typedef short bf16x8 __attribute__((ext_vector_type(8)));
typedef unsigned short us8 __attribute__((ext_vector_type(8)));
typedef unsigned int uint32x4 __attribute__((ext_vector_type(4)));

static __device__ __forceinline__ unsigned short f2bf(float x) {
  unsigned int u = __builtin_bit_cast(unsigned int, x);
  unsigned int r = (u + 0x7fffu + ((u >> 16) & 1u)) >> 16;  // RNE
  return (unsigned short)r;
}
static __device__ __forceinline__ float bf2f(unsigned short u) {
  unsigned int v = ((unsigned int)u) << 16;
  return __builtin_bit_cast(float, v);
}
static __device__ __forceinline__ float fastexp2(float x) {
  float r;
  asm("v_exp_f32 %0, %1" : "=v"(r) : "v"(x));
  return r;
}

// ---- K1: prep_small — fold head-mean + attention vecs into W fragments ----
// Bw layout: [kt(32)][h(2)][nf(3)][kh(2)][n(32)][e(8)] bf16 (192 KB).
__global__ __launch_bounds__(256) void prep_small(const float* __restrict__ W,
                                                  const float* __restrict__ a,
                                                  unsigned short* __restrict__ Bw) {
  const int kt = blockIdx.x;  // 0..31
  __shared__ float wm[16][64];
  __shared__ float wt[16][2];
  const int t = threadIdx.x;
#pragma unroll
  for (int i = 0; i < 4; ++i) {
    const int idx = t + i * 256;
    const int kr = idx >> 6, c = idx & 63;
    const float* wr = W + (size_t)(kt * 16 + kr) * FOUT + c;
    wm[kr][c] = 0.25f * (wr[0] + wr[64] + wr[128] + wr[192]);
  }
  if (t < 32) {
    const int kr = t & 15, sel = t >> 4;
    const float* wr = W + (size_t)(kt * 16 + kr) * FOUT;
    const float* av = a + sel * FOUT;
    float s = 0.f;
    for (int n = 0; n < FOUT; ++n) s += wr[n] * av[n];
    wt[kr][sel] = s * 1.44269504f;
  }
  __syncthreads();
#pragma unroll
  for (int i = 0; i < 12; ++i) {
    const int idx = t + i * 256;  // within-kt offset < 3072
    const int e = idx & 7, n = (idx >> 3) & 31, r2 = idx >> 8;
    const int khb = r2 & 1, q = r2 >> 1;
    const int nf = q % 3, h = q / 3;
    const int k = khb * 8 + e;
    float v = nf < 2 ? wm[k][nf * 32 + n]
                     : (n == 0 ? wt[k][0] : (n == 1 ? wt[k][1] : 0.f));
    const unsigned short hi = f2bf(v);
    Bw[(size_t)kt * 3072 + idx] = (h == 0) ? hi : f2bf(v - bf2f(hi));
  }
}

// ---- K2: convert_x — x f32 -> hi/lo bf16 A-fragments ----
__global__ __launch_bounds__(256) void convert_x(const float* __restrict__ X,
                                                 unsigned short* __restrict__ xf) {
  const int f = blockIdx.x * 256 + threadIdx.x;  // < 524288
  const int r = f & 31, kh = (f >> 5) & 1, kt = (f >> 6) & 31, mw = f >> 11;
  const float* src = X + (size_t)(mw * 32 + r) * FIN + kt * 16 + kh * 8;
  const float4 v0 = *(const float4*)src;
  const float4 v1 = *(const float4*)(src + 4);
  const float vv[8] = {v0.x, v0.y, v0.z, v0.w, v1.x, v1.y, v1.z, v1.w};
  us8 vh, vl;
#pragma unroll
  for (int e = 0; e < 8; ++e) {
    const unsigned short hi = f2bf(vv[e]);
    vh[e] = hi;
    vl[e] = f2bf(vv[e] - bf2f(hi));
  }
  const size_t b0 = ((size_t)(mw * 32 + kt) * 4 + kh) * 256 + (size_t)r * 8;
  *(us8*)(xf + b0) = vh;
  *(us8*)(xf + b0 + 512) = vl;  // h stride = 512 shorts
}

// ---- K3: gemm_whm — Whm = x @ Wm (hi/lo MFMA); writes Bg fragments + s ----
__global__ __launch_bounds__(192) void gemm_whm(const unsigned short* __restrict__ xf,
                                                const unsigned short* __restrict__ Bw,
                                                unsigned short* __restrict__ Bg,
                                                float* __restrict__ ssrc,
                                                float* __restrict__ sdst) {
  __shared__ float sred[32][2];
  const int mw = blockIdx.x;
  const int nf = threadIdx.x >> 6, lane = threadIdx.x & 63;
  const int l31 = lane & 31, kh = lane >> 5;
  f32x16 acc = (f32x16)(0.f);
  const unsigned short* ap = xf + ((size_t)(mw * 32) * 4 + kh) * 256 + l31 * 8;
  const unsigned short* bp = Bw + ((size_t)nf * 2 + kh) * 256 + l31 * 8;
#pragma unroll 4
  for (int kt = 0; kt < 32; ++kt) {
    const bf16x8 a_h = *(const bf16x8*)(ap + kt * 1024);
    const bf16x8 a_l = *(const bf16x8*)(ap + kt * 1024 + 512);
    const bf16x8 b_h = *(const bf16x8*)(bp + kt * 3072);
    const bf16x8 b_l = *(const bf16x8*)(bp + kt * 3072 + 1536);
    acc = __builtin_amdgcn_mfma_f32_32x32x16_bf16(a_h, b_h, acc, 0, 0, 0);
    acc = __builtin_amdgcn_mfma_f32_32x32x16_bf16(a_h, b_l, acc, 0, 0, 0);
    acc = __builtin_amdgcn_mfma_f32_32x32x16_bf16(a_l, b_h, acc, 0, 0, 0);
  }
  if (nf < 2) {
    // Bg per jw(=mw): [h(2)][kc(2)][khb(2)][nf(2)][nn(32)][e(8)] shorts.
    unsigned short* bgw = Bg + (size_t)mw * 4096;
#pragma unroll
    for (int reg = 0; reg < 16; ++reg) {
      const float v = acc[reg];
      const unsigned short hi = f2bf(v);
      const unsigned short lo = f2bf(v - bf2f(hi));
      const int e = (reg & 3) | (kh << 2);
      const int khb = (reg >> 2) & 1;
      const int kc = reg >> 3;
      const size_t off =
          (size_t)(((kc * 2 + khb) * 2 + nf) * 256) + l31 * 8 + e;
      bgw[off] = hi;
      bgw[off + 2048] = lo;
    }
  } else if (l31 < 2) {
#pragma unroll
    for (int reg = 0; reg < 16; ++reg) {
      const int row = (reg & 3) + ((reg >> 2) << 3) + (kh << 2);
      sred[row][l31] = acc[reg];
    }
  }
  __syncthreads();
  if (threadIdx.x < 32) {
    ssrc[mw * 32 + threadIdx.x] = sred[threadIdx.x][0];
    sdst[mw * 32 + threadIdx.x] = sred[threadIdx.x][1];
  }
}

// ---- K5: gat_aggr — FUSED adj read (ballot-pack in prologue) + MFMA loop ----
// grid 1024 = 32 bm x 32 bj; 512 thr / 8 waves; wave = 32 rows x 64 cols.
// Prologue: stage B slice (64 KB LDS, vmcnt) + read own 256x256 adj tile
// coalesced (lane=4 cols, 4 rounds x 8 rows) -> 4 u64 bitmask VGPRs per lane
// via __ballot + keep-select. Main loop: compute-only, no barriers.
#define GLL(G, L)                                                           \
  __builtin_amdgcn_global_load_lds(                                         \
      (const __attribute__((address_space(1))) unsigned int*)(G),           \
      (__attribute__((address_space(3))) unsigned int*)(L), 16, 0, 0)

// p = exp2( bit ? lr : 0 ); dacc sums raw f32 p.
#define PEL(P, MM, B, SD)                    \
  float P;                                   \
  {                                          \
    float tt = ss + (SD);                    \
    float lr = fmaxf(tt, 0.2f * tt);         \
    lr = (((MM) >> (B)) & 1u) ? lr : 0.0f;   \
    P = fastexp2(lr);                        \
    dacc += P;                               \
  }

// Word k bit layout: bit l of mb[k] = adj[row][chunk + 4l + k].
// Col within step-word: kc*4 + kh*2 + (e>>2) after per-step byte extraction;
// m_k pre-shifted by kh*2 => bit = (m_{e&3} >> (kc*4 + (e>>2))) & 1.
#define GENAF(AF, M0, M1, M2, M3, KC4, SA, SB)                            \
  {                                                                       \
    PEL(p0, M0, (KC4) + 0, (SA).x) PEL(p1, M1, (KC4) + 0, (SA).y)         \
    PEL(p2, M2, (KC4) + 0, (SA).z) PEL(p3, M3, (KC4) + 0, (SA).w)         \
    PEL(p4, M0, (KC4) + 1, (SB).x) PEL(p5, M1, (KC4) + 1, (SB).y)         \
    PEL(p6, M2, (KC4) + 1, (SB).z) PEL(p7, M3, (KC4) + 1, (SB).w)         \
    unsigned int w0, w1, w2, w3;                                          \
    asm("v_cvt_pk_bf16_f32 %0, %1, %2" : "=v"(w0) : "v"(p0), "v"(p1));    \
    asm("v_cvt_pk_bf16_f32 %0, %1, %2" : "=v"(w1) : "v"(p2), "v"(p3));    \
    asm("v_cvt_pk_bf16_f32 %0, %1, %2" : "=v"(w2) : "v"(p4), "v"(p5));    \
    asm("v_cvt_pk_bf16_f32 %0, %1, %2" : "=v"(w3) : "v"(p6), "v"(p7));    \
    const uint32x4 uv = {w0, w1, w2, w3};                                 \
    AF = __builtin_bit_cast(bf16x8, uv);                                  \
  }

__global__ __launch_bounds__(512, 4) void gat_aggr(
    const int* __restrict__ adj, const float* __restrict__ ssrc_g,
    const float* __restrict__ sdst_g, const unsigned short* __restrict__ Bg,
    unsigned short* __restrict__ Upb, float* __restrict__ Dp) {
  __shared__ unsigned short lbuf[STEPS * 4096];  // 64 KB: whole bj B slice
  const int bid = blockIdx.x;
  const int bj = bid & 31, bm = bid >> 5;
  const int wv = threadIdx.x >> 6, lane = threadIdx.x & 63;
  const int l31 = lane & 31, kh = lane >> 5;
  const int rbase = bm * 256;
  const int myrow = rbase + wv * 32 + l31;
  const int jb = bj * JCHUNK;
  const float ss = ssrc_g[myrow];
  const float* sdp = sdst_g + jb + kh * 8;

  // ---- stage B slice (vmcnt->LDS) ----
  {
    const unsigned short* gs = Bg + (size_t)bj * (STEPS * 4096) +
                               (size_t)(wv * 8) * 512 + lane * 8;
#pragma unroll
    for (int c = 0; c < 8; ++c) GLL(gs + c * 512, &lbuf[(wv * 8 + c) * 512]);
  }

  // ---- read own adj tile (coalesced), ballot-pack to 4 u64 per lane ----
  unsigned long long mb0 = 0, mb1 = 0, mb2 = 0, mb3 = 0;
  {
    const int* abase = adj + (size_t)(rbase + wv * 32) * NN + jb + lane * 4;
#pragma unroll 1
    for (int rd = 0; rd < 4; ++rd) {
      int4 q0 = *(const int4*)(abase + (size_t)(rd * 8 + 0) * NN);
      int4 q1 = *(const int4*)(abase + (size_t)(rd * 8 + 1) * NN);
      int4 q2 = *(const int4*)(abase + (size_t)(rd * 8 + 2) * NN);
      int4 q3 = *(const int4*)(abase + (size_t)(rd * 8 + 3) * NN);
      int4 q4 = *(const int4*)(abase + (size_t)(rd * 8 + 4) * NN);
      int4 q5 = *(const int4*)(abase + (size_t)(rd * 8 + 5) * NN);
      int4 q6 = *(const int4*)(abase + (size_t)(rd * 8 + 6) * NN);
      int4 q7 = *(const int4*)(abase + (size_t)(rd * 8 + 7) * NN);
#define BAL(Q, I)                                                   \
      {                                                             \
        unsigned long long b0 = __ballot((Q).x != 0);               \
        unsigned long long b1 = __ballot((Q).y != 0);               \
        unsigned long long b2 = __ballot((Q).z != 0);               \
        unsigned long long b3 = __ballot((Q).w != 0);               \
        const bool keep = (l31 == rd * 8 + (I));                    \
        mb0 = keep ? b0 : mb0;                                      \
        mb1 = keep ? b1 : mb1;                                      \
        mb2 = keep ? b2 : mb2;                                      \
        mb3 = keep ? b3 : mb3;                                      \
      }
      BAL(q0, 0) BAL(q1, 1) BAL(q2, 2) BAL(q3, 3)
      BAL(q4, 4) BAL(q5, 5) BAL(q6, 6) BAL(q7, 7)
#undef BAL
    }
  }

  f32x16 acc0 = (f32x16)(0.f), acc1 = (f32x16)(0.f);
  float dacc = 0.f;
  __syncthreads();  // B slice landed; only barrier in the kernel

  const unsigned short* lb0 = &lbuf[kh * 512 + l31 * 8];
  const int kh2 = kh * 2;

#pragma unroll 1
  for (int t = 0; t < STEPS; ++t) {
    const unsigned int m0 = ((unsigned int)mb0) >> kh2;
    const unsigned int m1 = ((unsigned int)mb1) >> kh2;
    const unsigned int m2 = ((unsigned int)mb2) >> kh2;
    const unsigned int m3 = ((unsigned int)mb3) >> kh2;
    mb0 >>= 8; mb1 >>= 8; mb2 >>= 8; mb3 >>= 8;
    const unsigned short* tb = lb0 + (size_t)t * 4096;
    const bf16x8 b00 = *(const bf16x8*)(tb);          // kc0 h0 nf0
    const bf16x8 b01 = *(const bf16x8*)(tb + 2048);   // kc0 h1 nf0
    const bf16x8 b02 = *(const bf16x8*)(tb + 256);    // kc0 h0 nf1
    const bf16x8 b03 = *(const bf16x8*)(tb + 2304);   // kc0 h1 nf1
    const bf16x8 b10 = *(const bf16x8*)(tb + 1024);   // kc1 h0 nf0
    const bf16x8 b11 = *(const bf16x8*)(tb + 3072);   // kc1 h1 nf0
    const bf16x8 b12 = *(const bf16x8*)(tb + 1280);   // kc1 h0 nf1
    const bf16x8 b13 = *(const bf16x8*)(tb + 3328);   // kc1 h1 nf1
    const float4 sA0 = *(const float4*)(sdp + t * 32);
    const float4 sB0 = *(const float4*)(sdp + t * 32 + 4);
    const float4 sA1 = *(const float4*)(sdp + t * 32 + 16);
    const float4 sB1 = *(const float4*)(sdp + t * 32 + 20);
    bf16x8 af0, af1;
    GENAF(af0, m0, m1, m2, m3, 0, sA0, sB0)
    GENAF(af1, m0, m1, m2, m3, 4, sA1, sB1)
    acc0 = __builtin_amdgcn_mfma_f32_32x32x16_bf16(af0, b00, acc0, 0, 0, 0);
    acc0 = __builtin_amdgcn_mfma_f32_32x32x16_bf16(af0, b01, acc0, 0, 0, 0);
    acc1 = __builtin_amdgcn_mfma_f32_32x32x16_bf16(af0, b02, acc1, 0, 0, 0);
    acc1 = __builtin_amdgcn_mfma_f32_32x32x16_bf16(af0, b03, acc1, 0, 0, 0);
    acc0 = __builtin_amdgcn_mfma_f32_32x32x16_bf16(af1, b10, acc0, 0, 0, 0);
    acc0 = __builtin_amdgcn_mfma_f32_32x32x16_bf16(af1, b11, acc0, 0, 0, 0);
    acc1 = __builtin_amdgcn_mfma_f32_32x32x16_bf16(af1, b12, acc1, 0, 0, 0);
    acc1 = __builtin_amdgcn_mfma_f32_32x32x16_bf16(af1, b13, acc1, 0, 0, 0);
  }

  // ---- D: lanes l, l+32 hold complementary kh halves of same row ----
  dacc += __shfl_xor(dacc, 32);
  if (lane < 32) Dp[(size_t)bj * NN + myrow] = dacc;

  // ---- U: C/D layout col=lane&31, row=(reg&3)+8*(reg>>2)+4*(lane>>5) ----
  unsigned short* ub = Upb + ((size_t)bj * NN + rbase + wv * 32) * FH;
#pragma unroll
  for (int reg = 0; reg < 16; ++reg) {
    const int rr = (reg & 3) + ((reg >> 2) << 3) + (kh << 2);
    ub[(size_t)rr * FH + l31] = f2bf(acc0[reg]);
    ub[(size_t)rr * FH + 32 + l31] = f2bf(acc1[reg]);
  }
}

// ---- K6: finalize — combine j-splits, divide ----
__global__ __launch_bounds__(256) void finalize(const unsigned short* __restrict__ Upb,
                                                const float* __restrict__ Dp,
                                                float* __restrict__ out) {
  const int idx = blockIdx.x * 256 + threadIdx.x;  // < 8192*64
  const int i = idx >> 6;
  float u = 0.f, d = 0.f;
#pragma unroll
  for (int s = 0; s < JSPLIT; ++s) {
    d += Dp[(size_t)s * NN + i];
    u += bf2f(Upb[(size_t)s * NN * FH + idx]);
  }
  out[idx] = u / d;
}

extern "C" void kernel_launch(void* const* d_in, const int* in_sizes, int n_in,
                              void* d_out, int out_size, void* d_ws, size_t ws_size,
                              hipStream_t stream) {
  const float* x = (const float*)d_in[0];
  const int* adj = (const int*)d_in[1];
  const float* W = (const float*)d_in[2];
  const float* a = (const float*)d_in[3];
  char* ws = (char*)d_ws;

  // ws layout (~37 MB):
  //   xf    [0, 16 MB)   bf16 hi/lo x-fragments (dead after gemm_whm)
  //   Upb   [0, 32 MB)   bf16 U partials (32 splits) -- OVERLAPS xf
  //   Bg    [32, 34 MB)  bf16 hi/lo Whm B-fragments (written by gemm_whm)
  //   Bw    36 MB +192 KB; ssrc +256K; sdst +288K; Dp +320K (1 MB)
  unsigned short* xf = (unsigned short*)ws;
  unsigned short* Upb = (unsigned short*)ws;
  unsigned short* Bg = (unsigned short*)(ws + ((size_t)32 << 20));
  unsigned short* Bw = (unsigned short*)(ws + ((size_t)36 << 20));
  float* ssrc = (float*)(ws + ((size_t)36 << 20) + (256u << 10));
  float* sdst = (float*)(ws + ((size_t)36 << 20) + (288u << 10));
  float* Dp = (float*)(ws + ((size_t)36 << 20) + (320u << 10));
  float* out = (float*)d_out;

  prep_small<<<32, 256, 0, stream>>>(W, a, Bw);
  convert_x<<<2048, 256, 0, stream>>>(x, xf);
  gemm_whm<<<256, 192, 0, stream>>>(xf, Bw, Bg, ssrc, sdst);
  gat_aggr<<<32 * JSPLIT, 512, 0, stream>>>(adj, ssrc, sdst, Bg, Upb, Dp);
  finalize<<<NN * FH / 256, 256, 0, stream>>>(Upb, Dp, out);
}